// Round 6
// baseline (249.883 us; speedup 1.0000x reference)
//
#include <hip/hip_runtime.h>
#include <hip/hip_bf16.h>
#include <stdint.h>

#define B_   256
#define S_   32
#define L_   20
#define D_   512
#define IN_  1024
#define M_ROWS 8448   // 256 self rows + 8192 social rows
#define NT   512      // embd dim
#define FBM  48       // fused GEMM M (33 real rows padded to 48)
#define ETS  516      // Etile row stride (f32), padded to break bank alignment
#define GRID_AGG 256  // persistent: 1 block/CU

typedef __attribute__((ext_vector_type(4))) float f32x4;
typedef __attribute__((ext_vector_type(8))) short s16x8;

static __device__ __forceinline__ float wave_reduce_sum(float v) {
#pragma unroll
  for (int off = 32; off > 0; off >>= 1) v += __shfl_xor(v, off);
  return v;
}

// ---------------------------------------------------------------------------
// K1: masked mean over L -> agg bf16 [8448][1024].
// Persistent blocks (1/CU), triple-buffered 40KB LDS chunks, depth-2 DMA
// prefetch with counted vmcnt (never 0 in main loop), raw s_barrier.
// Task = (row, users|items). 11 DMA ops/wave/task (10 data + 1 mask).
// ---------------------------------------------------------------------------
__global__ __launch_bounds__(256) void agg_kernel(
    const float* __restrict__ self_users, const float* __restrict__ self_items,
    const float* __restrict__ self_mask,
    const float* __restrict__ soc_users, const float* __restrict__ soc_items,
    const float* __restrict__ soc_mask,
    __hip_bfloat16* __restrict__ agg) {
  __shared__ __align__(16) float buf[3][L_ * D_];   // 3 x 40 KB
  __shared__ __align__(16) float maskbuf[3][64];
  const int tid = threadIdx.x;
  const int lane = tid & 63;
  const int nt = (2 * M_ROWS) / GRID_AGG;  // 66 tasks per block

  auto stage = [&](int it, int nb) {
    int task = blockIdx.x + it * GRID_AGG;
    int row = task >> 1, arr = task & 1;
    const float* src;
    const float* mptr;
    if (row < B_) {
      src = (arr ? self_items : self_users) + (size_t)row * (L_ * D_);
      mptr = self_mask + (size_t)row * L_;
    } else {
      int idx = row - B_;
      src = (arr ? soc_items : soc_users) + (size_t)idx * (L_ * D_);
      mptr = soc_mask + (size_t)idx * L_;
    }
    // mask: 4B/lane, source clamped in-bounds; all 4 waves write same data
    const float* msrc = mptr + (lane < L_ ? lane : L_ - 1);
    __builtin_amdgcn_global_load_lds(
        (const __attribute__((address_space(1))) void*)msrc,
        (__attribute__((address_space(3))) void*)&maskbuf[nb][0], 4, 0, 0);
    // data: 10 x (256 lanes x 16B), linear
#pragma unroll
    for (int k = 0; k < 10; ++k) {
      int off = (k * 256 + tid) * 4;
      __builtin_amdgcn_global_load_lds(
          (const __attribute__((address_space(1))) void*)(src + off),
          (__attribute__((address_space(3))) void*)(&buf[nb][0] + off), 16, 0, 0);
    }
  };

  // prologue: depth-2 prefetch
  stage(0, 0);
  stage(1, 1);

  for (int it = 0; it < nt; ++it) {
    int cb = it % 3;
    int task = blockIdx.x + it * GRID_AGG;
    if (it + 2 < nt) {
      stage(it + 2, (it + 2) % 3);
      __builtin_amdgcn_sched_barrier(0);
      asm volatile("s_waitcnt vmcnt(22)" ::: "memory");  // 2 tasks in flight
    } else if (it + 1 < nt) {
      __builtin_amdgcn_sched_barrier(0);
      asm volatile("s_waitcnt vmcnt(11)" ::: "memory");  // 1 task in flight
    } else {
      __builtin_amdgcn_sched_barrier(0);
      asm volatile("s_waitcnt vmcnt(0)" ::: "memory");
    }
    __builtin_amdgcn_sched_barrier(0);
    __builtin_amdgcn_s_barrier();   // all waves' DMA for buf[cb] done
    __builtin_amdgcn_sched_barrier(0);

    float mk[L_];
    float msum = 1e-4f;
#pragma unroll
    for (int l = 0; l < L_; ++l) { mk[l] = maskbuf[cb][l]; msum += mk[l]; }
    float inv = 1.0f / msum;
    float a0 = 0.f, a1 = 0.f;
#pragma unroll
    for (int l = 0; l < L_; ++l) {
      float2 v = *(const float2*)&buf[cb][l * D_ + tid * 2];
      a0 += mk[l] * v.x;
      a1 += mk[l] * v.y;
    }
    a0 *= inv;
    a1 *= inv;
    int row = task >> 1, arr = task & 1;
    __hip_bfloat16 h[2] = {__float2bfloat16(a0), __float2bfloat16(a1)};
    *(ushort2*)(agg + (size_t)row * IN_ + arr * D_ + tid * 2) = *(const ushort2*)h;

    __builtin_amdgcn_sched_barrier(0);
    __builtin_amdgcn_s_barrier();   // all waves done reading buf[cb] (reused it+3)
    __builtin_amdgcn_sched_barrier(0);
  }
}

// ---------------------------------------------------------------------------
// convert ml_user_w [512][1024] f32 -> bf16
// ---------------------------------------------------------------------------
__global__ __launch_bounds__(256) void cvt_w_kernel(
    const float* __restrict__ w, __hip_bfloat16* __restrict__ wb) {
  int i = (blockIdx.x * 256 + threadIdx.x) * 4;
  f32x4 v = *(const f32x4*)(w + i);
  __hip_bfloat16 h[4] = {__float2bfloat16(v[0]), __float2bfloat16(v[1]),
                         __float2bfloat16(v[2]), __float2bfloat16(v[3])};
  *(ushort4*)(wb + i) = *(const ushort4*)h;
}

// ---------------------------------------------------------------------------
// K2: per-user mega-fused kernel. Block b (512 threads, 8 waves):
//   phase 1: GEMM  Et[48][512] = relu(A[48][1024] @ W^T + bias)
//   phase 2: attention over rows 1..32 vs row 0, softmax, attn row.
//   phase 3: rate scores: w2 . relu(W1 @ e + b1) for e in {self, attn}.
// ---------------------------------------------------------------------------
__global__ __launch_bounds__(512) void fused_kernel(
    const __hip_bfloat16* __restrict__ agg, const __hip_bfloat16* __restrict__ wb,
    const float* __restrict__ bias,
    const float* __restrict__ W1, const float* __restrict__ b1,
    const float* __restrict__ w2,
    float* __restrict__ selfE, float* __restrict__ social_attn,
    float* __restrict__ scores) {
  int b = blockIdx.x;
  int tid = threadIdx.x, lane = tid & 63, wid = tid >> 6;

  __shared__ __align__(16) char smem[FBM * ETS * 4];  // 99072 B
  ushort* Asub = (ushort*)smem;        // [48][64] bf16 = 6144 B  (GEMM phase)
  ushort* Wsub = Asub + 3072;          // [512][64] bf16 = 65536 B (GEMM phase)
  float* Et = (float*)smem;            // [48][516] f32 (after GEMM)
  __shared__ float arow[NT];
  __shared__ float sc_sh[S_], att_sh[S_], wpS[8], wpA[8];

  int a_row = tid >> 3;                       // 0..47 for tid<384
  int a_g   = (tid & 7) ^ (a_row & 7);
  int growv = (a_row >= 1 && a_row <= 32) ? (B_ + b * S_ + a_row - 1) : b;
  const ushort* aggp = (const ushort*)agg + (size_t)growv * IN_ + a_g * 8;
  const ushort* wbp = (const ushort*)wb;

  f32x4 acc[3][4];
#pragma unroll
  for (int i = 0; i < 3; ++i)
#pragma unroll
    for (int j = 0; j < 4; ++j) acc[i][j] = {0.f, 0.f, 0.f, 0.f};

  for (int kt = 0; kt < IN_; kt += 64) {
    __syncthreads();
    if (tid < 384)  // waves 0..5, uniform
      __builtin_amdgcn_global_load_lds(
          (const __attribute__((address_space(1))) void*)(aggp + kt),
          (__attribute__((address_space(3))) void*)(Asub + tid * 8), 16, 0, 0);
#pragma unroll
    for (int it = 0; it < 8; ++it) {
      int s = it * 512 + tid;               // 0..4095
      int wrow = s >> 3;                    // 0..511
      int wg = (s & 7) ^ (wrow & 7);
      __builtin_amdgcn_global_load_lds(
          (const __attribute__((address_space(1))) void*)(wbp + (size_t)wrow * IN_ + kt + wg * 8),
          (__attribute__((address_space(3))) void*)(Wsub + s * 8), 16, 0, 0);
    }
    __syncthreads();
#pragma unroll
    for (int kk = 0; kk < 64; kk += 32) {
      s16x8 af[3], bf[4];
#pragma unroll
      for (int i = 0; i < 3; ++i) {
        int row = i * 16 + (lane & 15);
        int g = ((kk >> 3) + (lane >> 4)) ^ (row & 7);
        af[i] = *(const s16x8*)(Asub + row * 64 + g * 8);
      }
#pragma unroll
      for (int j = 0; j < 4; ++j) {
        int wrow = wid * 64 + j * 16 + (lane & 15);
        int g = ((kk >> 3) + (lane >> 4)) ^ (wrow & 7);
        bf[j] = *(const s16x8*)(Wsub + wrow * 64 + g * 8);
      }
#pragma unroll
      for (int i = 0; i < 3; ++i)
#pragma unroll
        for (int j = 0; j < 4; ++j)
          acc[i][j] = __builtin_amdgcn_mfma_f32_16x16x32_bf16(af[i], bf[j], acc[i][j], 0, 0, 0);
    }
  }
  __syncthreads();  // staging region now dead; reuse as Et

  // epilogue: bias + relu -> Et. C/D layout col=lane&15, row=(lane>>4)*4+q.
#pragma unroll
  for (int j = 0; j < 4; ++j) {
    int col = wid * 64 + j * 16 + (lane & 15);
    float bv = bias[col];
#pragma unroll
    for (int i = 0; i < 3; ++i) {
#pragma unroll
      for (int q = 0; q < 4; ++q) {
        int row = i * 16 + (lane >> 4) * 4 + q;
        float v = acc[i][j][q] + bv;
        Et[row * ETS + col] = v > 0.f ? v : 0.f;
      }
    }
  }
  __syncthreads();

  // --- attention: dots of rows 1..32 vs row 0 (each wave: 4 rows)
  {
    f32x4 s0 = *(const f32x4*)&Et[lane * 8];
    f32x4 s1 = *(const f32x4*)&Et[lane * 8 + 4];
#pragma unroll
    for (int q = 0; q < 4; ++q) {
      int s = wid * 4 + q + 1;
      f32x4 v0 = *(const f32x4*)&Et[s * ETS + lane * 8];
      f32x4 v1 = *(const f32x4*)&Et[s * ETS + lane * 8 + 4];
      float p = s0[0]*v0[0] + s0[1]*v0[1] + s0[2]*v0[2] + s0[3]*v0[3]
              + s1[0]*v1[0] + s1[1]*v1[1] + s1[2]*v1[2] + s1[3]*v1[3];
      p = wave_reduce_sum(p);
      if (lane == 0) sc_sh[s - 1] = p;
    }
  }
  __syncthreads();
  if (wid == 0) {
    float v = (lane < S_) ? sc_sh[lane] : -3.4e38f;
    float m = v;
#pragma unroll
    for (int off = 16; off > 0; off >>= 1) m = fmaxf(m, __shfl_xor(m, off));
    float e = (lane < S_) ? expf(v - m) : 0.f;
    float sum = e;
#pragma unroll
    for (int off = 16; off > 0; off >>= 1) sum += __shfl_xor(sum, off);
    if (lane < S_) att_sh[lane] = e / sum;
  }
  __syncthreads();
  // weighted sum over social rows; also export self row
  {
    float a = 0.f;
#pragma unroll 8
    for (int s = 1; s <= S_; ++s) a += att_sh[s - 1] * Et[s * ETS + tid];
    arow[tid] = a;
    social_attn[(size_t)b * NT + tid] = a;
    selfE[(size_t)b * NT + tid] = Et[tid];
  }
  __syncthreads();

  // --- rate scores: stream W1 rows (f32, coalesced), dual dot self/attn
  {
    f32x4 es0 = *(const f32x4*)&Et[lane * 8];
    f32x4 es1 = *(const f32x4*)&Et[lane * 8 + 4];
    f32x4 ea0 = *(const f32x4*)&arow[lane * 8];
    f32x4 ea1 = *(const f32x4*)&arow[lane * 8 + 4];
    float accS = 0.f, accA = 0.f;
    for (int r = wid; r < D_; r += 8) {
      const float* wr_ = W1 + (size_t)r * D_ + lane * 8;
      f32x4 w0 = *(const f32x4*)wr_;
      f32x4 w1v = *(const f32x4*)(wr_ + 4);
      float pS = es0[0]*w0[0] + es0[1]*w0[1] + es0[2]*w0[2] + es0[3]*w0[3]
               + es1[0]*w1v[0] + es1[1]*w1v[1] + es1[2]*w1v[2] + es1[3]*w1v[3];
      float pA = ea0[0]*w0[0] + ea0[1]*w0[1] + ea0[2]*w0[2] + ea0[3]*w0[3]
               + ea1[0]*w1v[0] + ea1[1]*w1v[1] + ea1[2]*w1v[2] + ea1[3]*w1v[3];
#pragma unroll
      for (int off = 32; off > 0; off >>= 1) {
        pS += __shfl_xor(pS, off);
        pA += __shfl_xor(pA, off);
      }
      float bv = b1[r], wv = w2[r];
      float tS = pS + bv; tS = tS > 0.f ? tS : 0.f;
      float tA = pA + bv; tA = tA > 0.f ? tA : 0.f;
      accS += wv * tS;
      accA += wv * tA;
    }
    if (lane == 0) { wpS[wid] = accS; wpA[wid] = accA; }
  }
  __syncthreads();
  if (tid == 0) {
    float s = 0.f;
#pragma unroll
    for (int k = 0; k < 8; ++k) s += wpS[k];
    scores[b] = s;
  }
  if (tid == 1) {
    float s = 0.f;
#pragma unroll
    for (int k = 0; k < 8; ++k) s += wpA[k];
    scores[B_ + b] = s;
  }
}

// ---------------------------------------------------------------------------
// K3: batch softmax (recomputed per block) + partial pool over 32 users.
// ---------------------------------------------------------------------------
__global__ __launch_bounds__(256) void pool_partial_kernel(
    const float* __restrict__ selfE, const float* __restrict__ social_attn,
    const float* __restrict__ scores, float* __restrict__ partial) {
  int v = blockIdx.x >> 3;
  int chunk = blockIdx.x & 7;
  const float* E = v ? social_attn : selfE;
  const float* sc = scores + v * B_;
  __shared__ float att[B_];
  __shared__ float red[8];
  int tid = threadIdx.x, lane = tid & 63, wid = tid >> 6;
  float s = sc[tid];
  float m = s;
#pragma unroll
  for (int off = 32; off > 0; off >>= 1) m = fmaxf(m, __shfl_xor(m, off));
  if (lane == 0) red[wid] = m;
  __syncthreads();
  m = fmaxf(fmaxf(red[0], red[1]), fmaxf(red[2], red[3]));
  float ev = expf(s - m);
  float sum = wave_reduce_sum(ev);
  if (lane == 0) red[4 + wid] = sum;
  __syncthreads();
  sum = red[4] + red[5] + red[6] + red[7];
  att[tid] = ev / sum;
  __syncthreads();
  float a0 = 0.f, a1 = 0.f;
#pragma unroll 8
  for (int q = 0; q < 32; ++q) {
    int b = chunk * 32 + q;
    float w = att[b];
    a0 += w * E[(size_t)b * NT + tid];
    a1 += w * E[(size_t)b * NT + tid + 256];
  }
  partial[(size_t)blockIdx.x * NT + tid] = a0;
  partial[(size_t)blockIdx.x * NT + tid + 256] = a1;
}

// ---------------------------------------------------------------------------
// K4: final reduce of 8 partials per v -> out[v][512]
// ---------------------------------------------------------------------------
__global__ __launch_bounds__(256) void pool_final_kernel(
    const float* __restrict__ partial, float* __restrict__ out) {
  int v = blockIdx.x;
  int tid = threadIdx.x;
  float a0 = 0.f, a1 = 0.f;
#pragma unroll
  for (int c = 0; c < 8; ++c) {
    const float* p = partial + (size_t)(v * 8 + c) * NT;
    a0 += p[tid];
    a1 += p[tid + 256];
  }
  out[v * NT + tid] = a0;
  out[v * NT + tid + 256] = a1;
}

// ---------------------------------------------------------------------------
extern "C" void kernel_launch(void* const* d_in, const int* in_sizes, int n_in,
                              void* d_out, int out_size, void* d_ws, size_t ws_size,
                              hipStream_t stream) {
  const float* self_users = (const float*)d_in[0];
  const float* self_items = (const float*)d_in[1];
  const float* self_mask  = (const float*)d_in[2];
  const float* soc_users  = (const float*)d_in[3];
  const float* soc_items  = (const float*)d_in[4];
  const float* soc_mask   = (const float*)d_in[5];
  const float* ml_user_w  = (const float*)d_in[6];
  const float* ml_user_b  = (const float*)d_in[7];
  const float* ml_w1      = (const float*)d_in[8];
  const float* ml_b1      = (const float*)d_in[9];
  const float* ml_w2      = (const float*)d_in[10];

  char* ws = (char*)d_ws;
  __hip_bfloat16* agg = (__hip_bfloat16*)ws;               // 17,301,504 B
  __hip_bfloat16* wb  = (__hip_bfloat16*)(ws + 17301504);  //  1,048,576 B
  float* selfE        = (float*)(ws + 18350080);           //    524,288 B
  float* social_attn  = (float*)(ws + 18874368);           //    524,288 B
  float* scores       = (float*)(ws + 19398656);           //      2,048 B
  float* partial      = (float*)(ws + 19400704);           //     32,768 B

  hipLaunchKernelGGL(agg_kernel, dim3(GRID_AGG), dim3(256), 0, stream,
                     self_users, self_items, self_mask, soc_users, soc_items,
                     soc_mask, agg);
  hipLaunchKernelGGL(cvt_w_kernel, dim3(512), dim3(256), 0, stream, ml_user_w, wb);
  hipLaunchKernelGGL(fused_kernel, dim3(B_), dim3(512), 0, stream,
                     agg, wb, ml_user_b, ml_w1, ml_b1, ml_w2,
                     selfE, social_attn, scores);
  hipLaunchKernelGGL(pool_partial_kernel, dim3(16), dim3(256), 0, stream,
                     selfE, social_attn, scores, partial);
  hipLaunchKernelGGL(pool_final_kernel, dim3(2), dim3(256), 0, stream,
                     partial, (float*)d_out);
}

// Round 7
// 189.607 us; speedup vs baseline: 1.3179x; 1.3179x over previous
//
#include <hip/hip_runtime.h>
#include <hip/hip_bf16.h>
#include <stdint.h>

#define B_   256
#define S_   32
#define L_   20
#define D_   512
#define IN_  1024
#define M_ROWS 8448   // 256 self rows + 8192 social rows
#define NT   512      // embd dim
#define FBM  48       // fused GEMM M (33 real rows padded to 48)
#define ETS  516      // Etile row stride (f32), padded to break bank alignment

typedef __attribute__((ext_vector_type(4))) float f32x4;
typedef __attribute__((ext_vector_type(8))) short s16x8;

static __device__ __forceinline__ float wave_reduce_sum(float v) {
#pragma unroll
  for (int off = 32; off > 0; off >>= 1) v += __shfl_xor(v, off);
  return v;
}

// ---------------------------------------------------------------------------
// K1: masked mean over L -> agg bf16 [8448][1024]; blocks >= M_ROWS convert
// ml_user_w f32 -> bf16.
// Streaming-read test: __builtin_nontemporal_load (nt cache policy — bypass
// L2/L3 allocation for the once-read 693MB stream) + sched_barrier(0) after
// the load block so ALL 20 dwordx4 are issued before first use (forced MLP;
// the compiler cannot re-serialize to save VGPRs).
// ---------------------------------------------------------------------------
__global__ __launch_bounds__(256) void agg_cvt_kernel(
    const float* __restrict__ self_users, const float* __restrict__ self_items,
    const float* __restrict__ self_mask,
    const float* __restrict__ soc_users, const float* __restrict__ soc_items,
    const float* __restrict__ soc_mask,
    const float* __restrict__ w,
    __hip_bfloat16* __restrict__ agg, __hip_bfloat16* __restrict__ wb) {
  int r = blockIdx.x;
  int tid = threadIdx.x;
  if (r >= M_ROWS) {
    // W cast: 128 blocks x 4096 elements
    int base = (r - M_ROWS) * 4096 + tid * 16;
#pragma unroll
    for (int u = 0; u < 4; ++u) {
      f32x4 v = *(const f32x4*)(w + base + u * 4);
      __hip_bfloat16 h[4] = {__float2bfloat16(v[0]), __float2bfloat16(v[1]),
                             __float2bfloat16(v[2]), __float2bfloat16(v[3])};
      *(ushort4*)(wb + base + u * 4) = *(const ushort4*)h;
    }
    return;
  }
  const float *uptr, *iptr, *mptr;
  if (r < B_) {
    uptr = self_users + (size_t)r * (L_ * D_);
    iptr = self_items + (size_t)r * (L_ * D_);
    mptr = self_mask + (size_t)r * L_;
  } else {
    int idx = r - B_;
    uptr = soc_users + (size_t)idx * (L_ * D_);
    iptr = soc_items + (size_t)idx * (L_ * D_);
    mptr = soc_mask + (size_t)idx * L_;
  }

  // Issue ALL 20 nontemporal dwordx4 loads; nothing may cross the barrier.
  const float* base = ((tid < 128) ? uptr : iptr) + (tid & 127) * 4;
  f32x4 v[L_];
#pragma unroll
  for (int l = 0; l < L_; ++l)
    v[l] = __builtin_nontemporal_load((const f32x4*)(base + (size_t)l * D_));

  // Mask: block-uniform scalar loads (SGPR), overlap with the stream.
  float mk[L_];
  float msum = 1e-4f;
#pragma unroll
  for (int l = 0; l < L_; ++l) { mk[l] = mptr[l]; msum += mk[l]; }
  float inv = 1.0f / msum;

  __builtin_amdgcn_sched_barrier(0);  // all loads issued before any use

  f32x4 acc = {0.f, 0.f, 0.f, 0.f};
#pragma unroll
  for (int l = 0; l < L_; ++l) acc += v[l] * mk[l];
  acc *= inv;

  __hip_bfloat16 h[4] = {__float2bfloat16(acc[0]), __float2bfloat16(acc[1]),
                         __float2bfloat16(acc[2]), __float2bfloat16(acc[3])};
  size_t o = (size_t)r * IN_ + ((tid < 128) ? 0 : D_) + (tid & 127) * 4;
  *(ushort4*)(agg + o) = *(const ushort4*)h;
}

// ---------------------------------------------------------------------------
// K2: per-user mega-fused kernel. Block b (512 threads, 8 waves):
//   phase 1: GEMM  Et[48][512] = relu(A[48][1024] @ W^T + bias)
//   phase 2: attention over rows 1..32 vs row 0, softmax, attn row.
//   phase 3: rate scores: w2 . relu(W1 @ e + b1) for e in {self, attn}.
// ---------------------------------------------------------------------------
__global__ __launch_bounds__(512) void fused_kernel(
    const __hip_bfloat16* __restrict__ agg, const __hip_bfloat16* __restrict__ wb,
    const float* __restrict__ bias,
    const float* __restrict__ W1, const float* __restrict__ b1,
    const float* __restrict__ w2,
    float* __restrict__ selfE, float* __restrict__ social_attn,
    float* __restrict__ scores) {
  int b = blockIdx.x;
  int tid = threadIdx.x, lane = tid & 63, wid = tid >> 6;

  __shared__ __align__(16) char smem[FBM * ETS * 4];  // 99072 B
  ushort* Asub = (ushort*)smem;        // [48][64] bf16 = 6144 B  (GEMM phase)
  ushort* Wsub = Asub + 3072;          // [512][64] bf16 = 65536 B (GEMM phase)
  float* Et = (float*)smem;            // [48][516] f32 (after GEMM)
  __shared__ float arow[NT];
  __shared__ float sc_sh[S_], att_sh[S_], wpS[8], wpA[8];

  int a_row = tid >> 3;                       // 0..47 for tid<384
  int a_g   = (tid & 7) ^ (a_row & 7);
  int growv = (a_row >= 1 && a_row <= 32) ? (B_ + b * S_ + a_row - 1) : b;
  const ushort* aggp = (const ushort*)agg + (size_t)growv * IN_ + a_g * 8;
  const ushort* wbp = (const ushort*)wb;

  f32x4 acc[3][4];
#pragma unroll
  for (int i = 0; i < 3; ++i)
#pragma unroll
    for (int j = 0; j < 4; ++j) acc[i][j] = {0.f, 0.f, 0.f, 0.f};

  for (int kt = 0; kt < IN_; kt += 64) {
    __syncthreads();
    if (tid < 384)  // waves 0..5, uniform
      __builtin_amdgcn_global_load_lds(
          (const __attribute__((address_space(1))) void*)(aggp + kt),
          (__attribute__((address_space(3))) void*)(Asub + tid * 8), 16, 0, 0);
#pragma unroll
    for (int it = 0; it < 8; ++it) {
      int s = it * 512 + tid;               // 0..4095
      int wrow = s >> 3;                    // 0..511
      int wg = (s & 7) ^ (wrow & 7);
      __builtin_amdgcn_global_load_lds(
          (const __attribute__((address_space(1))) void*)(wbp + (size_t)wrow * IN_ + kt + wg * 8),
          (__attribute__((address_space(3))) void*)(Wsub + s * 8), 16, 0, 0);
    }
    __syncthreads();
#pragma unroll
    for (int kk = 0; kk < 64; kk += 32) {
      s16x8 af[3], bf[4];
#pragma unroll
      for (int i = 0; i < 3; ++i) {
        int row = i * 16 + (lane & 15);
        int g = ((kk >> 3) + (lane >> 4)) ^ (row & 7);
        af[i] = *(const s16x8*)(Asub + row * 64 + g * 8);
      }
#pragma unroll
      for (int j = 0; j < 4; ++j) {
        int wrow = wid * 64 + j * 16 + (lane & 15);
        int g = ((kk >> 3) + (lane >> 4)) ^ (wrow & 7);
        bf[j] = *(const s16x8*)(Wsub + wrow * 64 + g * 8);
      }
#pragma unroll
      for (int i = 0; i < 3; ++i)
#pragma unroll
        for (int j = 0; j < 4; ++j)
          acc[i][j] = __builtin_amdgcn_mfma_f32_16x16x32_bf16(af[i], bf[j], acc[i][j], 0, 0, 0);
    }
  }
  __syncthreads();  // staging region now dead; reuse as Et

  // epilogue: bias + relu -> Et. C/D layout col=lane&15, row=(lane>>4)*4+q.
#pragma unroll
  for (int j = 0; j < 4; ++j) {
    int col = wid * 64 + j * 16 + (lane & 15);
    float bv = bias[col];
#pragma unroll
    for (int i = 0; i < 3; ++i) {
#pragma unroll
      for (int q = 0; q < 4; ++q) {
        int row = i * 16 + (lane >> 4) * 4 + q;
        float v = acc[i][j][q] + bv;
        Et[row * ETS + col] = v > 0.f ? v : 0.f;
      }
    }
  }
  __syncthreads();

  // --- attention: dots of rows 1..32 vs row 0 (each wave: 4 rows)
  {
    f32x4 s0 = *(const f32x4*)&Et[lane * 8];
    f32x4 s1 = *(const f32x4*)&Et[lane * 8 + 4];
#pragma unroll
    for (int q = 0; q < 4; ++q) {
      int s = wid * 4 + q + 1;
      f32x4 v0 = *(const f32x4*)&Et[s * ETS + lane * 8];
      f32x4 v1 = *(const f32x4*)&Et[s * ETS + lane * 8 + 4];
      float p = s0[0]*v0[0] + s0[1]*v0[1] + s0[2]*v0[2] + s0[3]*v0[3]
              + s1[0]*v1[0] + s1[1]*v1[1] + s1[2]*v1[2] + s1[3]*v1[3];
      p = wave_reduce_sum(p);
      if (lane == 0) sc_sh[s - 1] = p;
    }
  }
  __syncthreads();
  if (wid == 0) {
    float v = (lane < S_) ? sc_sh[lane] : -3.4e38f;
    float m = v;
#pragma unroll
    for (int off = 16; off > 0; off >>= 1) m = fmaxf(m, __shfl_xor(m, off));
    float e = (lane < S_) ? expf(v - m) : 0.f;
    float sum = e;
#pragma unroll
    for (int off = 16; off > 0; off >>= 1) sum += __shfl_xor(sum, off);
    if (lane < S_) att_sh[lane] = e / sum;
  }
  __syncthreads();
  // weighted sum over social rows; also export self row
  {
    float a = 0.f;
#pragma unroll 8
    for (int s = 1; s <= S_; ++s) a += att_sh[s - 1] * Et[s * ETS + tid];
    arow[tid] = a;
    social_attn[(size_t)b * NT + tid] = a;
    selfE[(size_t)b * NT + tid] = Et[tid];
  }
  __syncthreads();

  // --- rate scores: stream W1 rows (f32, coalesced), dual dot self/attn
  {
    f32x4 es0 = *(const f32x4*)&Et[lane * 8];
    f32x4 es1 = *(const f32x4*)&Et[lane * 8 + 4];
    f32x4 ea0 = *(const f32x4*)&arow[lane * 8];
    f32x4 ea1 = *(const f32x4*)&arow[lane * 8 + 4];
    float accS = 0.f, accA = 0.f;
    for (int r = wid; r < D_; r += 8) {
      const float* wr_ = W1 + (size_t)r * D_ + lane * 8;
      f32x4 w0 = *(const f32x4*)wr_;
      f32x4 w1v = *(const f32x4*)(wr_ + 4);
      float pS = es0[0]*w0[0] + es0[1]*w0[1] + es0[2]*w0[2] + es0[3]*w0[3]
               + es1[0]*w1v[0] + es1[1]*w1v[1] + es1[2]*w1v[2] + es1[3]*w1v[3];
      float pA = ea0[0]*w0[0] + ea0[1]*w0[1] + ea0[2]*w0[2] + ea0[3]*w0[3]
               + ea1[0]*w1v[0] + ea1[1]*w1v[1] + ea1[2]*w1v[2] + ea1[3]*w1v[3];
#pragma unroll
      for (int off = 32; off > 0; off >>= 1) {
        pS += __shfl_xor(pS, off);
        pA += __shfl_xor(pA, off);
      }
      float bv = b1[r], wv = w2[r];
      float tS = pS + bv; tS = tS > 0.f ? tS : 0.f;
      float tA = pA + bv; tA = tA > 0.f ? tA : 0.f;
      accS += wv * tS;
      accA += wv * tA;
    }
    if (lane == 0) { wpS[wid] = accS; wpA[wid] = accA; }
  }
  __syncthreads();
  if (tid == 0) {
    float s = 0.f;
#pragma unroll
    for (int k = 0; k < 8; ++k) s += wpS[k];
    scores[b] = s;
  }
  if (tid == 1) {
    float s = 0.f;
#pragma unroll
    for (int k = 0; k < 8; ++k) s += wpA[k];
    scores[B_ + b] = s;
  }
}

// ---------------------------------------------------------------------------
// K3: batch softmax (recomputed per block) + partial pool over 32 users.
// ---------------------------------------------------------------------------
__global__ __launch_bounds__(256) void pool_partial_kernel(
    const float* __restrict__ selfE, const float* __restrict__ social_attn,
    const float* __restrict__ scores, float* __restrict__ partial) {
  int v = blockIdx.x >> 3;
  int chunk = blockIdx.x & 7;
  const float* E = v ? social_attn : selfE;
  const float* sc = scores + v * B_;
  __shared__ float att[B_];
  __shared__ float red[8];
  int tid = threadIdx.x, lane = tid & 63, wid = tid >> 6;
  float s = sc[tid];
  float m = s;
#pragma unroll
  for (int off = 32; off > 0; off >>= 1) m = fmaxf(m, __shfl_xor(m, off));
  if (lane == 0) red[wid] = m;
  __syncthreads();
  m = fmaxf(fmaxf(red[0], red[1]), fmaxf(red[2], red[3]));
  float ev = expf(s - m);
  float sum = wave_reduce_sum(ev);
  if (lane == 0) red[4 + wid] = sum;
  __syncthreads();
  sum = red[4] + red[5] + red[6] + red[7];
  att[tid] = ev / sum;
  __syncthreads();
  float a0 = 0.f, a1 = 0.f;
#pragma unroll 8
  for (int q = 0; q < 32; ++q) {
    int b = chunk * 32 + q;
    float w = att[b];
    a0 += w * E[(size_t)b * NT + tid];
    a1 += w * E[(size_t)b * NT + tid + 256];
  }
  partial[(size_t)blockIdx.x * NT + tid] = a0;
  partial[(size_t)blockIdx.x * NT + tid + 256] = a1;
}

// ---------------------------------------------------------------------------
// K4: final reduce of 8 partials per v -> out[v][512]
// ---------------------------------------------------------------------------
__global__ __launch_bounds__(256) void pool_final_kernel(
    const float* __restrict__ partial, float* __restrict__ out) {
  int v = blockIdx.x;
  int tid = threadIdx.x;
  float a0 = 0.f, a1 = 0.f;
#pragma unroll
  for (int c = 0; c < 8; ++c) {
    const float* p = partial + (size_t)(v * 8 + c) * NT;
    a0 += p[tid];
    a1 += p[tid + 256];
  }
  out[v * NT + tid] = a0;
  out[v * NT + tid + 256] = a1;
}

// ---------------------------------------------------------------------------
extern "C" void kernel_launch(void* const* d_in, const int* in_sizes, int n_in,
                              void* d_out, int out_size, void* d_ws, size_t ws_size,
                              hipStream_t stream) {
  const float* self_users = (const float*)d_in[0];
  const float* self_items = (const float*)d_in[1];
  const float* self_mask  = (const float*)d_in[2];
  const float* soc_users  = (const float*)d_in[3];
  const float* soc_items  = (const float*)d_in[4];
  const float* soc_mask   = (const float*)d_in[5];
  const float* ml_user_w  = (const float*)d_in[6];
  const float* ml_user_b  = (const float*)d_in[7];
  const float* ml_w1      = (const float*)d_in[8];
  const float* ml_b1      = (const float*)d_in[9];
  const float* ml_w2      = (const float*)d_in[10];

  char* ws = (char*)d_ws;
  __hip_bfloat16* agg = (__hip_bfloat16*)ws;               // 17,301,504 B
  __hip_bfloat16* wb  = (__hip_bfloat16*)(ws + 17301504);  //  1,048,576 B
  float* selfE        = (float*)(ws + 18350080);           //    524,288 B
  float* social_attn  = (float*)(ws + 18874368);           //    524,288 B
  float* scores       = (float*)(ws + 19398656);           //      2,048 B
  float* partial      = (float*)(ws + 19400704);           //     32,768 B

  hipLaunchKernelGGL(agg_cvt_kernel, dim3(M_ROWS + 128), dim3(256), 0, stream,
                     self_users, self_items, self_mask, soc_users, soc_items,
                     soc_mask, ml_user_w, agg, wb);
  hipLaunchKernelGGL(fused_kernel, dim3(B_), dim3(512), 0, stream,
                     agg, wb, ml_user_b, ml_w1, ml_b1, ml_w2,
                     selfE, social_attn, scores);
  hipLaunchKernelGGL(pool_partial_kernel, dim3(16), dim3(256), 0, stream,
                     selfE, social_attn, scores, partial);
  hipLaunchKernelGGL(pool_final_kernel, dim3(2), dim3(256), 0, stream,
                     partial, (float*)d_out);
}